// Round 5
// baseline (987.373 us; speedup 1.0000x reference)
//
#include <hip/hip_runtime.h>
#include <math.h>

#define NCH     129
#define NT      250
#define DINNER  256
#define DSTATE  16
#define NHEADS  4
#define DPROJ   548   // z(256) + xh(256) + B(16) + C(16) + dt(4)
#define TC      16    // timestep chunk; 250 = 15*16 + 10
#define NCHUNK  16

template<int N> struct IC { static constexpr int value = N; };

__device__ __forceinline__ float silu_f(float x) { return x / (1.f + __expf(-x)); }

// DPP butterfly: after 6 steps lane 63 holds the 64-lane sum (VALU pipe, no DS).
template<int CTRL>
__device__ __forceinline__ float dstep(float v) {
    int t = __builtin_amdgcn_update_dpp(0, __float_as_int(v), CTRL, 0xF, 0xF, true);
    return v + __int_as_float(t);
}
__device__ __forceinline__ float wave_sum63(float v) {
    v = dstep<0xB1>(v);   // quad_perm xor1
    v = dstep<0x4E>(v);   // quad_perm xor2
    v = dstep<0x141>(v);  // row_half_mirror
    v = dstep<0x140>(v);  // row_mirror
    v = dstep<0x142>(v);  // row_bcast15
    v = dstep<0x143>(v);  // row_bcast31 -> lane63 = total
    return v;
}
__device__ __forceinline__ float rdlane(float v, int l) {
    return __uint_as_float(__builtin_amdgcn_readlane(__float_as_uint(v), l));
}

// ---------- prep: W2t[c][j] = sum_d in_proj_w[j,d]*mixer_w[d,c]; bias2[j] ----------
__global__ __launch_bounds__(256) void k_prep_w2(const float* __restrict__ in_proj_w,
                                                 const float* __restrict__ mixer_w,
                                                 const float* __restrict__ mixer_b,
                                                 float* __restrict__ w2t,
                                                 float* __restrict__ bias2) {
    int j = blockIdx.x;
    int c = threadIdx.x;
    if (c < NCH) {
        float acc = 0.f;
        for (int d = 0; d < 128; ++d)
            acc += in_proj_w[j * 128 + d] * mixer_w[d * NCH + c];
        w2t[(size_t)c * DPROJ + j] = acc;
    } else if (c == NCH) {
        float acc = 0.f;
        for (int d = 0; d < 128; ++d)
            acc += in_proj_w[j * 128 + d] * mixer_b[d];
        bias2[j] = acc;
    }
}

// ---------- prep: v[i] = sum_d head_w[0,d]*out_proj_w[d,i] ----------
__global__ __launch_bounds__(256) void k_prep_v(const float* __restrict__ head_w,
                                                const float* __restrict__ out_proj_w,
                                                float* __restrict__ v) {
    int i = threadIdx.x;
    float acc = 0.f;
    for (int d = 0; d < 128; ++d)
        acc += head_w[d] * out_proj_w[(size_t)d * DINNER + i];
    v[i] = acc;
}

// ---------- fused pipeline: 5 waves; waves 0-3 = 256 channels, wave 4 = staging/BC/dt/reduce ----------
__global__ __launch_bounds__(320, 2) void k_fused(
    const float* __restrict__ x,        // [B,129,250]
    const float* __restrict__ w2t,      // [129,548]
    const float* __restrict__ bias2,    // [548]
    const float* __restrict__ conv_w,   // [288,4]
    const float* __restrict__ conv_b,   // [288]
    const float* __restrict__ dt_bias,  // [4]
    const float* __restrict__ A_log,    // [4]
    const float* __restrict__ Dv,       // [4]
    const float* __restrict__ norm_w,   // [256]
    const float* __restrict__ vv,       // [256]
    const float* __restrict__ head_b,   // [1]
    float* __restrict__ out)            // [B]
{
    __shared__ float xbuf[2][NCH * TC];       // staged x chunk: [c*16 + t]
    __shared__ float valbuf[2][TC][DINNER];   // scan outputs awaiting reduction
    __shared__ float bcbuf[2][TC][32];        // [tt][0..15 B | 16..31 C]
    __shared__ float dtbuf[2][TC][NHEADS];
    __shared__ float dAbuf[2][TC][NHEADS];

    const int b    = blockIdx.x;
    const int tid  = threadIdx.x;
    const int lane = tid & 63;
    const bool isMain = (tid < 256);
    const int p = tid;           // main: channel
    const int q = lane;          // aux: role

    float bz = 0.f, bx = 0.f;
    float cw0 = 0.f, cw1 = 0.f, cw2 = 0.f, cw3 = 0.f, ccb = 0.f;
    float dtb = 0.f, Ah = 0.f, Dh = 0.f;
    float4 nv4 = make_float4(0.f, 0.f, 0.f, 0.f);
    int j1 = 0, j2 = 0;
    if (isMain) {
        j1 = p; j2 = DINNER + p;
        bz = bias2[j1]; bx = bias2[j2];
        cw0 = conv_w[p * 4 + 0]; cw1 = conv_w[p * 4 + 1];
        cw2 = conv_w[p * 4 + 2]; cw3 = conv_w[p * 4 + 3];
        ccb = conv_b[p];
        Dh = Dv[p >> 6];
    } else {
        if (q < 36) {
            j2 = 2 * DINNER + q;
            bx = bias2[j2];
            if (q < 32) {
                int ch = DINNER + q;
                cw0 = conv_w[ch * 4 + 0]; cw1 = conv_w[ch * 4 + 1];
                cw2 = conv_w[ch * 4 + 2]; cw3 = conv_w[ch * 4 + 3];
                ccb = conv_b[ch];
            } else {
                int h = q - 32;
                dtb = dt_bias[h];
                Ah  = -expf(A_log[h]);
            }
        }
        nv4.x = norm_w[4 * q + 0] * vv[4 * q + 0];
        nv4.y = norm_w[4 * q + 1] * vv[4 * q + 1];
        nv4.z = norm_w[4 * q + 2] * vv[4 * q + 2];
        nv4.w = norm_w[4 * q + 3] * vv[4 * q + 3];
    }

    float za[TC], xa[TC], hs[DSTATE];
    float c1 = 0.f, c2 = 0.f, c3 = 0.f, outacc = 0.f;
#pragma unroll
    for (int n = 0; n < DSTATE; ++n) hs[n] = 0.f;

    const float* xb = x + (size_t)b * NCH * NT;
    const int hh = p >> 6;   // head (main, wave-uniform)

    // ---- aux: stage a chunk of x into LDS (coalesced float2) ----
    auto stage_x = [&](auto Lc, int buf, int t0) {
        constexpr int LEN = decltype(Lc)::value;
        if constexpr (LEN > 0) {
            constexpr int HW = LEN / 2;          // float2 per row
            for (int u = lane; u < NCH * HW; u += 64) {
                int c = u / HW, pr = u - c * HW;
                float2 v2 = *(const float2*)(xb + c * NT + t0 + 2 * pr);
                *(float2*)&xbuf[buf][c * TC + 2 * pr] = v2;
            }
        }
    };

    auto do_stage = [&](auto CLc, auto NLc, auto PLc, int s) {
        constexpr int CL = decltype(CLc)::value;   // current chunk len
        constexpr int NL = decltype(NLc)::value;   // next chunk len (stage ahead)
        constexpr int PL = decltype(PLc)::value;   // previous chunk len (reduce)
        const int cur = s & 1;

        if (isMain) {
            if constexpr (CL > 0) {
                // ---------- GEMM from LDS-broadcast x ----------
#pragma unroll
                for (int tt = 0; tt < CL; ++tt) { za[tt] = bz; xa[tt] = bx; }
                const float* wp1 = w2t + j1;
                const float* wp2 = w2t + j2;
                for (int c = 0; c < NCH; ++c) {
                    float w1  = wp1[c * DPROJ];
                    float w2v = wp2[c * DPROJ];
                    const float* xc = &xbuf[cur][c * TC];
                    float xv[16];
#pragma unroll
                    for (int k = 0; k < (CL + 3) / 4; ++k)
                        *(float4*)&xv[4 * k] = *(const float4*)&xc[4 * k];
#pragma unroll
                    for (int tt = 0; tt < CL; ++tt) {
                        za[tt] = fmaf(w1,  xv[tt], za[tt]);
                        xa[tt] = fmaf(w2v, xv[tt], xa[tt]);
                    }
                }
                // ---------- conv + silu ----------
#pragma unroll
                for (int tt = 0; tt < CL; ++tt) {
                    float raw = xa[tt];
                    float cv = fmaf(cw3, raw, fmaf(cw2, c1, fmaf(cw1, c2, fmaf(cw0, c3, ccb))));
                    c3 = c2; c2 = c1; c1 = raw;
                    xa[tt] = silu_f(cv);
                    za[tt] = silu_f(za[tt]);
                }
            }
        } else {
            if constexpr (NL > 0) stage_x(IC<NL>{}, (s + 1) & 1, (s + 1) * TC);
            if constexpr (CL > 0) {
                if (q < 36) {
#pragma unroll
                    for (int tt = 0; tt < CL; ++tt) xa[tt] = bx;
                    const float* wp2 = w2t + j2;
                    for (int c = 0; c < NCH; ++c) {
                        float w2v = wp2[c * DPROJ];
                        const float* xc = &xbuf[cur][c * TC];
                        float xv[16];
#pragma unroll
                        for (int k = 0; k < (CL + 3) / 4; ++k)
                            *(float4*)&xv[4 * k] = *(const float4*)&xc[4 * k];
#pragma unroll
                        for (int tt = 0; tt < CL; ++tt)
                            xa[tt] = fmaf(w2v, xv[tt], xa[tt]);
                    }
                    if (q < 32) {
#pragma unroll
                        for (int tt = 0; tt < CL; ++tt) {
                            float raw = xa[tt];
                            float cv = fmaf(cw3, raw, fmaf(cw2, c1, fmaf(cw1, c2, fmaf(cw0, c3, ccb))));
                            c3 = c2; c2 = c1; c1 = raw;
                            bcbuf[cur][tt][q] = silu_f(cv);
                        }
                    } else {
                        int h = q - 32;
#pragma unroll
                        for (int tt = 0; tt < CL; ++tt) {
                            float val = xa[tt] + dtb;
                            float dt = (val > 20.f) ? val : log1pf(expf(val));
                            dtbuf[cur][tt][h] = dt;
                            dAbuf[cur][tt][h] = __expf(dt * Ah);
                        }
                    }
                }
            }
            if constexpr (PL > 0) {
                // ---------- reduce previous chunk (all 64 aux lanes) ----------
                const int prv = (s - 1) & 1;
#pragma unroll
                for (int tt = 0; tt < PL; ++tt) {
                    float4 v4 = *(const float4*)&valbuf[prv][tt][4 * lane];
                    float s1 = fmaf(v4.x, v4.x, fmaf(v4.y, v4.y, fmaf(v4.z, v4.z, v4.w * v4.w)));
                    float s2 = fmaf(v4.x, nv4.x, fmaf(v4.y, nv4.y, fmaf(v4.z, nv4.z, v4.w * nv4.w)));
                    s1 = wave_sum63(s1);
                    s2 = wave_sum63(s2);
                    if (lane == 63)
                        outacc = fmaf(s2, rsqrtf(fmaf(s1, 1.f / DINNER, 1e-5f)), outacc);
                }
            }
        }
        __syncthreads();   // A: bc/dt[cur] ready; valbuf[prev] consumed; xbuf[cur] was ready from prev stage
        if (isMain) {
            if constexpr (CL > 0) {
                // ---------- scan ----------
#pragma unroll
                for (int tt = 0; tt < CL; ++tt) {
                    float xv  = xa[tt];
                    float g   = za[tt];
                    float dtv = dtbuf[cur][tt][hh];
                    float dAv = dAbuf[cur][tt][hh];
                    float bcv = bcbuf[cur][tt][lane & 31];
                    float dx = dtv * xv;
                    float y = 0.f;
#pragma unroll
                    for (int n = 0; n < DSTATE; ++n) {
                        float Bn = rdlane(bcv, n);
                        float Cn = rdlane(bcv, DSTATE + n);
                        hs[n] = fmaf(hs[n], dAv, dx * Bn);
                        y = fmaf(hs[n], Cn, y);
                    }
                    valbuf[cur][tt][p] = fmaf(Dh, xv, y) * g;
                }
            }
        }
        __syncthreads();   // B: valbuf[cur] written; xbuf[next] staged
    };

    // prologue: stage chunk 0
    if (!isMain) stage_x(IC<TC>{}, 0, 0);
    __syncthreads();

    do_stage(IC<16>{}, IC<16>{}, IC<0>{}, 0);
    for (int s = 1; s <= 13; ++s)
        do_stage(IC<16>{}, IC<16>{}, IC<16>{}, s);
    do_stage(IC<16>{}, IC<10>{}, IC<16>{}, 14);
    do_stage(IC<10>{}, IC<0>{},  IC<16>{}, 15);
    do_stage(IC<0>{},  IC<0>{},  IC<10>{}, 16);

    if (!isMain && lane == 63)
        out[b] = head_b[0] + outacc * (1.f / NT);
}

extern "C" void kernel_launch(void* const* d_in, const int* in_sizes, int n_in,
                              void* d_out, int out_size, void* d_ws, size_t ws_size,
                              hipStream_t stream) {
    const float* x         = (const float*)d_in[0];
    const float* mixer_w   = (const float*)d_in[1];
    const float* mixer_b   = (const float*)d_in[2];
    const float* in_proj_w = (const float*)d_in[3];
    const float* conv_w    = (const float*)d_in[4];
    const float* conv_b    = (const float*)d_in[5];
    const float* dt_bias   = (const float*)d_in[6];
    const float* A_log     = (const float*)d_in[7];
    const float* Dp        = (const float*)d_in[8];
    const float* norm_w    = (const float*)d_in[9];
    const float* out_proj_w= (const float*)d_in[10];
    const float* head_w    = (const float*)d_in[11];
    const float* head_b    = (const float*)d_in[12];
    float* out = (float*)d_out;

    int B = in_sizes[0] / (NCH * NT);   // 512

    float* ws    = (float*)d_ws;
    float* w2t   = ws;                          // 129*548
    float* bias2 = w2t + (size_t)NCH * DPROJ;   // 548
    float* vvp   = bias2 + DPROJ;               // 256

    k_prep_w2<<<DPROJ, 256, 0, stream>>>(in_proj_w, mixer_w, mixer_b, w2t, bias2);
    k_prep_v<<<1, 256, 0, stream>>>(head_w, out_proj_w, vvp);
    k_fused<<<B, 320, 0, stream>>>(x, w2t, bias2, conv_w, conv_b, dt_bias,
                                   A_log, Dp, norm_w, vvp, head_b, out);
}

// Round 6
// 803.440 us; speedup vs baseline: 1.2289x; 1.2289x over previous
//
#include <hip/hip_runtime.h>
#include <math.h>

#define NCH     129
#define NT      250
#define DINNER  256
#define DSTATE  16
#define NHEADS  4
#define DPROJ   548   // z(256) + xh(256) + B(16) + C(16) + dt(4)
#define TC      8     // timestep chunk; 250 = 31*8 + 2
#define MT      35    // M tiles of 16 (560 >= 548)
#define KSTEPS  5     // K steps of 32 (160 >= 129)
#define XROW    18    // padded LDS row for x chunk (bank-spread, 8B-aligned)

typedef __attribute__((ext_vector_type(8))) short short8;
typedef __attribute__((ext_vector_type(4))) float f32x4;

template<int N> struct IC { static constexpr int value = N; };

__device__ __forceinline__ float silu_f(float x) { return x / (1.f + __expf(-x)); }

// DPP butterfly: after 6 steps lane 63 holds the 64-lane sum (VALU pipe, no DS).
template<int CTRL>
__device__ __forceinline__ float dstep(float v) {
    int t = __builtin_amdgcn_update_dpp(0, __float_as_int(v), CTRL, 0xF, 0xF, true);
    return v + __int_as_float(t);
}
__device__ __forceinline__ float wave_sum63(float v) {
    v = dstep<0xB1>(v);   // quad_perm xor1
    v = dstep<0x4E>(v);   // quad_perm xor2
    v = dstep<0x141>(v);  // row_half_mirror
    v = dstep<0x140>(v);  // row_mirror
    v = dstep<0x142>(v);  // row_bcast15
    v = dstep<0x143>(v);  // row_bcast31 -> lane63 = total
    return v;
}
__device__ __forceinline__ float rdlane(float v, int l) {
    return __uint_as_float(__builtin_amdgcn_readlane(__float_as_uint(v), l));
}
__device__ __forceinline__ unsigned short f2bf(float f) {   // round-to-nearest-even
    unsigned u = __float_as_uint(f);
    u += 0x7FFF + ((u >> 16) & 1);
    return (unsigned short)(u >> 16);
}
__device__ __forceinline__ float bf2f(unsigned short h) {
    return __uint_as_float(((unsigned)h) << 16);
}

// ---------- prep: W2t[c][j] = sum_d in_proj_w[j,d]*mixer_w[d,c]; bias2[j] ----------
__global__ __launch_bounds__(256) void k_prep_w2(const float* __restrict__ in_proj_w,
                                                 const float* __restrict__ mixer_w,
                                                 const float* __restrict__ mixer_b,
                                                 float* __restrict__ w2t,
                                                 float* __restrict__ bias2) {
    int j = blockIdx.x;
    int c = threadIdx.x;
    if (c < NCH) {
        float acc = 0.f;
        for (int d = 0; d < 128; ++d)
            acc += in_proj_w[j * 128 + d] * mixer_w[d * NCH + c];
        w2t[(size_t)c * DPROJ + j] = acc;
    } else if (c == NCH) {
        float acc = 0.f;
        for (int d = 0; d < 128; ++d)
            acc += in_proj_w[j * 128 + d] * mixer_b[d];
        bias2[j] = acc;
    }
}

// ---------- prep: v[i] = sum_d head_w[0,d]*out_proj_w[d,i] ----------
__global__ __launch_bounds__(256) void k_prep_v(const float* __restrict__ head_w,
                                                const float* __restrict__ out_proj_w,
                                                float* __restrict__ v) {
    int i = threadIdx.x;
    float acc = 0.f;
    for (int d = 0; d < 128; ++d)
        acc += head_w[d] * out_proj_w[(size_t)d * DINNER + i];
    v[i] = acc;
}

// ---------- prep: split-bf16 A-fragments of W2 (M=j, K=c), 16x16x32 layout ----------
// A[m=mt*16+(lane&15)][k=ks*32+(lane>>4)*8+i]; zero-padded for k>=129, m>=548.
__global__ __launch_bounds__(64) void k_prep_frag(const float* __restrict__ w2t,
                                                  unsigned short* __restrict__ ahi,
                                                  unsigned short* __restrict__ alo) {
    int mt = blockIdx.x, ks = blockIdx.y;
    int lane = threadIdx.x;
    int m = mt * 16 + (lane & 15);
    size_t base = (((size_t)(mt * KSTEPS + ks)) * 64 + lane) * 8;
    for (int i = 0; i < 8; ++i) {
        int k = ks * 32 + (lane >> 4) * 8 + i;
        float v = (k < NCH && m < DPROJ) ? w2t[(size_t)k * DPROJ + m] : 0.f;
        unsigned short hb = f2bf(v);
        float lo = v - bf2f(hb);
        ahi[base + i] = hb;
        alo[base + i] = f2bf(lo);
    }
}

// ---------- fused: MFMA GEMM + conv + dt + scan + gated RMSNorm + dot v + mean ----------
// One block per batch element; 320 thr = 5 waves. Waves 0-3: 256 channels (MFMA over
// M-tiles, then per-channel conv/scan). Wave 4: x staging + B/C/dt + fold.
__global__ __launch_bounds__(320, 2) void k_fused(
    const float* __restrict__ x,        // [B,129,250]
    const unsigned short* __restrict__ ahi,
    const unsigned short* __restrict__ alo,
    const float* __restrict__ bias2,    // [548]
    const float* __restrict__ conv_w,   // [288,4]
    const float* __restrict__ conv_b,   // [288]
    const float* __restrict__ dt_bias,  // [4]
    const float* __restrict__ A_log,    // [4]
    const float* __restrict__ Dv,       // [4]
    const float* __restrict__ norm_w,   // [256]
    const float* __restrict__ vv,       // [256]
    const float* __restrict__ head_b,   // [1]
    float* __restrict__ out)            // [B]
{
    __shared__ float xbuf[160 * XROW];        // [c][t(16 slots)], rows>=129 stay zero
    __shared__ float zxbuf[TC * DPROJ];       // [tt][j]
    __shared__ float bcbuf[TC][32];           // [tt][0..15 B | 16..31 C]
    __shared__ float dtbuf[TC][NHEADS];
    __shared__ float dAbuf[TC][NHEADS];
    __shared__ float smp[2][TC][8];           // per-wave partials: [tt][2w]=s1,[2w+1]=s2

    const int b    = blockIdx.x;
    const int tid  = threadIdx.x;
    const int lane = tid & 63;
    const int wv   = tid >> 6;
    const bool isMain = (wv < 4);
    const int p    = tid;                 // main channel
    const int q    = lane;                // aux role
    const int tcol = lane & 15;
    const int quad = lane >> 4;

    float bz = 0.f, bx = 0.f;
    float cw0 = 0.f, cw1 = 0.f, cw2 = 0.f, cw3 = 0.f, ccb = 0.f;
    float dtb = 0.f, Ah = 0.f, Dh = 0.f, nv = 0.f;
    if (isMain) {
        bz = bias2[p]; bx = bias2[DINNER + p];
        cw0 = conv_w[p * 4 + 0]; cw1 = conv_w[p * 4 + 1];
        cw2 = conv_w[p * 4 + 2]; cw3 = conv_w[p * 4 + 3];
        ccb = conv_b[p];
        Dh = Dv[p >> 6];
        nv = norm_w[p] * vv[p];
    } else if (q < 36) {
        bx = bias2[2 * DINNER + q];
        if (q < 32) {
            int ch = DINNER + q;
            cw0 = conv_w[ch * 4 + 0]; cw1 = conv_w[ch * 4 + 1];
            cw2 = conv_w[ch * 4 + 2]; cw3 = conv_w[ch * 4 + 3];
            ccb = conv_b[ch];
        } else {
            int h = q - 32;
            dtb = dt_bias[h];
            Ah  = -expf(A_log[h]);
        }
    }

    float za[TC], xa[TC], hs[DSTATE];
    float c1 = 0.f, c2 = 0.f, c3 = 0.f, outacc = 0.f;
#pragma unroll
    for (int n = 0; n < DSTATE; ++n) hs[n] = 0.f;

    const float* xb = x + (size_t)b * NCH * NT;
    const int hh = p >> 6;
    float2 pr[9];

    // aux: prefetch a chunk of x into registers (coalesced float2)
    auto load_chunk = [&](int t0, auto Lc) {
        constexpr int L  = decltype(Lc)::value;
        constexpr int HP = L / 2;
        constexpr int PAIRS = NCH * HP;
#pragma unroll
        for (int k = 0; k * 64 < PAIRS; ++k) {
            int u = lane + 64 * k;
            if (u < PAIRS) {
                int c = u / HP, tp = u - c * HP;
                pr[k] = *(const float2*)(xb + c * NT + t0 + 2 * tp);
            }
        }
    };
    auto store_chunk = [&](auto Lc) {
        constexpr int L  = decltype(Lc)::value;
        constexpr int HP = L / 2;
        constexpr int PAIRS = NCH * HP;
#pragma unroll
        for (int k = 0; k * 64 < PAIRS; ++k) {
            int u = lane + 64 * k;
            if (u < PAIRS) {
                int c = u / HP, tp = u - c * HP;
                *(float2*)&xbuf[c * XROW + 2 * tp] = pr[k];
            }
        }
    };

    // prologue: zero xbuf (pad rows/cols), stage chunk 0
    for (int u = tid; u < 160 * XROW; u += 320) xbuf[u] = 0.f;
    if (!isMain) load_chunk(0, IC<TC>{});
    __syncthreads();
    if (!isMain) store_chunk(IC<TC>{});
    __syncthreads();

    auto stage = [&](auto CLc, auto NLc, auto PLc, int s) {
        constexpr int CL = decltype(CLc)::value;
        constexpr int NL = decltype(NLc)::value;
        constexpr int PL = decltype(PLc)::value;
        const int cur = s & 1;

        // ---------------- P1: MFMA GEMM into zxbuf ----------------
        if (isMain) {
            short8 bh[KSTEPS], bl[KSTEPS];
#pragma unroll
            for (int ks = 0; ks < KSTEPS; ++ks) {
#pragma unroll
                for (int i = 0; i < 8; ++i) {
                    float fv = xbuf[(ks * 32 + quad * 8 + i) * XROW + tcol];
                    unsigned short hb = f2bf(fv);
                    bh[ks][i] = (short)hb;
                    bl[ks][i] = (short)f2bf(fv - bf2f(hb));
                }
            }
            for (int mt = wv; mt < MT; mt += 4) {
                f32x4 a0 = {0.f, 0.f, 0.f, 0.f};
                f32x4 a1 = {0.f, 0.f, 0.f, 0.f};
#pragma unroll
                for (int ks = 0; ks < KSTEPS; ++ks) {
                    size_t fo = (((size_t)(mt * KSTEPS + ks)) * 64 + lane) * 8;
                    short8 ah = *(const short8*)(ahi + fo);
                    short8 al = *(const short8*)(alo + fo);
                    a0 = __builtin_amdgcn_mfma_f32_16x16x32_bf16(ah, bh[ks], a0, 0, 0, 0);
                    a1 = __builtin_amdgcn_mfma_f32_16x16x32_bf16(ah, bl[ks], a1, 0, 0, 0);
                    a1 = __builtin_amdgcn_mfma_f32_16x16x32_bf16(al, bh[ks], a1, 0, 0, 0);
                }
                if (tcol < CL) {
#pragma unroll
                    for (int r = 0; r < 4; ++r) {
                        int j = mt * 16 + quad * 4 + r;
                        if (j < DPROJ) zxbuf[tcol * DPROJ + j] = a0[r] + a1[r];
                    }
                }
            }
        } else {
            if (s > 0 && PL > 0) {      // fold previous chunk's partials
                if (q < PL) {
                    const float* sp = smp[(s - 1) & 1][q];
                    float s1 = sp[0] + sp[2] + sp[4] + sp[6];
                    float s2 = sp[1] + sp[3] + sp[5] + sp[7];
                    outacc = fmaf(s2, rsqrtf(fmaf(s1, 1.f / DINNER, 1e-5f)), outacc);
                }
            }
            if (NL > 0) load_chunk((s + 1) * TC, IC<(NL > 0 ? NL : 2)>{});
        }
        __syncthreads();   // A: zxbuf ready; xbuf consumed (B-frags built)

        // ---------------- P2a: read own columns, conv+silu; aux: bc/dt + stage next x ----
        if (isMain) {
#pragma unroll
            for (int tt = 0; tt < CL; ++tt) {
                float zraw = zxbuf[tt * DPROJ + p] + bz;
                float xraw = zxbuf[tt * DPROJ + DINNER + p] + bx;
                float cv = fmaf(cw3, xraw, fmaf(cw2, c1, fmaf(cw1, c2, fmaf(cw0, c3, ccb))));
                c3 = c2; c2 = c1; c1 = xraw;
                xa[tt] = silu_f(cv);
                za[tt] = silu_f(zraw);
            }
        } else {
            if (NL > 0) store_chunk(IC<(NL > 0 ? NL : 2)>{});
            if (q < 32) {
#pragma unroll
                for (int tt = 0; tt < CL; ++tt) {
                    float raw = zxbuf[tt * DPROJ + 2 * DINNER + q] + bx;
                    float cv = fmaf(cw3, raw, fmaf(cw2, c1, fmaf(cw1, c2, fmaf(cw0, c3, ccb))));
                    c3 = c2; c2 = c1; c1 = raw;
                    bcbuf[tt][q] = silu_f(cv);
                }
            } else if (q < 36) {
                int h = q - 32;
#pragma unroll
                for (int tt = 0; tt < CL; ++tt) {
                    float val = zxbuf[tt * DPROJ + 544 + h] + bx + dtb;
                    float dt = (val > 20.f) ? val : log1pf(expf(val));
                    dtbuf[tt][h] = dt;
                    dAbuf[tt][h] = __expf(dt * Ah);
                }
            }
        }
        __syncthreads();   // B: bcbuf/dtbuf ready; xbuf restaged for next stage

        // ---------------- P2b: scan + DPP reductions ----------------
        if (isMain) {
#pragma unroll
            for (int tt = 0; tt < CL; ++tt) {
                float xv  = xa[tt];
                float g   = za[tt];
                float dtv = dtbuf[tt][hh];
                float dAv = dAbuf[tt][hh];
                float bcv = bcbuf[tt][lane & 31];
                float dx = dtv * xv;
                float y0 = 0.f, y1 = 0.f, y2 = 0.f, y3 = 0.f;
#pragma unroll
                for (int n = 0; n < 4; ++n) {
                    float b0 = rdlane(bcv, n),      cc0 = rdlane(bcv, DSTATE + n);
                    float b1 = rdlane(bcv, 4 + n),  cc1 = rdlane(bcv, DSTATE + 4 + n);
                    float b2 = rdlane(bcv, 8 + n),  cc2 = rdlane(bcv, DSTATE + 8 + n);
                    float b3 = rdlane(bcv, 12 + n), cc3 = rdlane(bcv, DSTATE + 12 + n);
                    hs[n]      = fmaf(hs[n],      dAv, dx * b0);  y0 = fmaf(hs[n],      cc0, y0);
                    hs[4 + n]  = fmaf(hs[4 + n],  dAv, dx * b1);  y1 = fmaf(hs[4 + n],  cc1, y1);
                    hs[8 + n]  = fmaf(hs[8 + n],  dAv, dx * b2);  y2 = fmaf(hs[8 + n],  cc2, y2);
                    hs[12 + n] = fmaf(hs[12 + n], dAv, dx * b3);  y3 = fmaf(hs[12 + n], cc3, y3);
                }
                float val = fmaf(Dh, xv, (y0 + y1) + (y2 + y3)) * g;
                float s1 = wave_sum63(val * val);
                float s2 = wave_sum63(val * nv);
                if (lane == 63) {
                    smp[cur][tt][2 * wv]     = s1;
                    smp[cur][tt][2 * wv + 1] = s2;
                }
            }
        }
        __syncthreads();   // C: smp written; zxbuf free; xbuf ready
    };

    stage(IC<8>{}, IC<8>{}, IC<0>{}, 0);
    for (int s = 1; s <= 29; ++s) stage(IC<8>{}, IC<8>{}, IC<8>{}, s);
    stage(IC<8>{}, IC<2>{}, IC<8>{}, 30);
    stage(IC<2>{}, IC<0>{}, IC<8>{}, 31);

    if (!isMain) {
        if (q < 2) {   // fold final (tail) chunk, stage 31, CL=2
            const float* sp = smp[31 & 1][q];
            float s1 = sp[0] + sp[2] + sp[4] + sp[6];
            float s2 = sp[1] + sp[3] + sp[5] + sp[7];
            outacc = fmaf(s2, rsqrtf(fmaf(s1, 1.f / DINNER, 1e-5f)), outacc);
        }
        float tot = wave_sum63(outacc);
        if (lane == 63) out[b] = head_b[0] + tot * (1.f / NT);
    }
}

extern "C" void kernel_launch(void* const* d_in, const int* in_sizes, int n_in,
                              void* d_out, int out_size, void* d_ws, size_t ws_size,
                              hipStream_t stream) {
    const float* x         = (const float*)d_in[0];
    const float* mixer_w   = (const float*)d_in[1];
    const float* mixer_b   = (const float*)d_in[2];
    const float* in_proj_w = (const float*)d_in[3];
    const float* conv_w    = (const float*)d_in[4];
    const float* conv_b    = (const float*)d_in[5];
    const float* dt_bias   = (const float*)d_in[6];
    const float* A_log     = (const float*)d_in[7];
    const float* Dp        = (const float*)d_in[8];
    const float* norm_w    = (const float*)d_in[9];
    const float* out_proj_w= (const float*)d_in[10];
    const float* head_w    = (const float*)d_in[11];
    const float* head_b    = (const float*)d_in[12];
    float* out = (float*)d_out;

    int B = in_sizes[0] / (NCH * NT);   // 512

    float* ws    = (float*)d_ws;
    float* w2t   = ws;                          // 129*548 f32
    float* bias2 = w2t + (size_t)NCH * DPROJ;   // 548
    float* vvp   = bias2 + DPROJ;               // 256
    unsigned short* ahi = (unsigned short*)(vvp + DINNER);       // 35*5*64*8
    unsigned short* alo = ahi + (size_t)MT * KSTEPS * 64 * 8;

    k_prep_w2<<<DPROJ, 256, 0, stream>>>(in_proj_w, mixer_w, mixer_b, w2t, bias2);
    k_prep_v<<<1, 256, 0, stream>>>(head_w, out_proj_w, vvp);
    k_prep_frag<<<dim3(MT, KSTEPS), 64, 0, stream>>>(w2t, ahi, alo);
    k_fused<<<B, 320, 0, stream>>>(x, ahi, alo, bias2, conv_w, conv_b, dt_bias,
                                   A_log, Dp, norm_w, vvp, head_b, out);
}

// Round 7
// 429.372 us; speedup vs baseline: 2.2996x; 1.8712x over previous
//
#include <hip/hip_runtime.h>
#include <math.h>

#define NCH     129
#define NT      250
#define DINNER  256
#define DSTATE  16
#define NHEADS  4
#define DPROJ   548   // z(256) + xh(256) + B(16) + C(16) + dt(4)
#define TC      8     // timesteps per chunk; 250 = 31*8 + 2
#define MT      35    // M tiles of 16 (560 >= 548)
#define KS4     4     // K steps of 32 (c=0..127); c=128 via VALU
#define ZR      17    // zxbuf col stride (16 cols + 1 pad)
#define XK      136   // xh/xl row stride in shorts (16B-aligned)

typedef __attribute__((ext_vector_type(8))) short short8;
typedef __attribute__((ext_vector_type(4))) float f32x4;

template<int N> struct IC { static constexpr int value = N; };

__device__ __forceinline__ float silu_f(float x) { return x / (1.f + __expf(-x)); }

template<int CTRL>
__device__ __forceinline__ float dstep(float v) {
    int t = __builtin_amdgcn_update_dpp(0, __float_as_int(v), CTRL, 0xF, 0xF, true);
    return v + __int_as_float(t);
}
__device__ __forceinline__ float wave_sum63(float v) {
    v = dstep<0xB1>(v);  v = dstep<0x4E>(v);  v = dstep<0x141>(v);
    v = dstep<0x140>(v); v = dstep<0x142>(v); v = dstep<0x143>(v);
    return v;   // lane 63 = total
}
__device__ __forceinline__ float rdlane(float v, int l) {
    return __uint_as_float(__builtin_amdgcn_readlane(__float_as_uint(v), l));
}
__device__ __forceinline__ unsigned short f2bf(float f) {   // RNE
    unsigned u = __float_as_uint(f);
    u += 0x7FFF + ((u >> 16) & 1);
    return (unsigned short)(u >> 16);
}
__device__ __forceinline__ float bf2f(unsigned short h) {
    return __uint_as_float(((unsigned)h) << 16);
}

// ---------- prep: W2t[c][j] = in_proj_w @ mixer_w (fused); bias2[j] ----------
__global__ __launch_bounds__(256) void k_prep_w2(const float* __restrict__ in_proj_w,
                                                 const float* __restrict__ mixer_w,
                                                 const float* __restrict__ mixer_b,
                                                 float* __restrict__ w2t,
                                                 float* __restrict__ bias2) {
    int j = blockIdx.x;
    int c = threadIdx.x;
    if (c < NCH) {
        float acc = 0.f;
        for (int d = 0; d < 128; ++d)
            acc += in_proj_w[j * 128 + d] * mixer_w[d * NCH + c];
        w2t[(size_t)c * DPROJ + j] = acc;
    } else if (c == NCH) {
        float acc = 0.f;
        for (int d = 0; d < 128; ++d)
            acc += in_proj_w[j * 128 + d] * mixer_b[d];
        bias2[j] = acc;
    }
}

// ---------- prep: v[i] = head_w @ out_proj_w ----------
__global__ __launch_bounds__(256) void k_prep_v(const float* __restrict__ head_w,
                                                const float* __restrict__ out_proj_w,
                                                float* __restrict__ v) {
    int i = threadIdx.x;
    float acc = 0.f;
    for (int d = 0; d < 128; ++d)
        acc += head_w[d] * out_proj_w[(size_t)d * DINNER + i];
    v[i] = acc;
}

// ---------- prep: split-bf16 A-frags of W2 (KS4 k-steps, c<128), 16x16x32 layout ----------
__global__ __launch_bounds__(64) void k_prep_frag(const float* __restrict__ w2t,
                                                  unsigned short* __restrict__ ahi,
                                                  unsigned short* __restrict__ alo) {
    int mt = blockIdx.x, ks = blockIdx.y;
    int lane = threadIdx.x;
    int m = mt * 16 + (lane & 15);
    size_t base = (((size_t)(mt * KS4 + ks)) * 64 + lane) * 8;
    for (int i = 0; i < 8; ++i) {
        int k = ks * 32 + (lane >> 4) * 8 + i;   // < 128 always
        float v = (m < DPROJ) ? w2t[(size_t)k * DPROJ + m] : 0.f;
        unsigned short hb = f2bf(v);
        ahi[base + i] = hb;
        alo[base + i] = f2bf(v - bf2f(hb));
    }
}

// ---------- fused: 2 batches/block, 640 thr = 10 waves ----------
// waves 0-3: batch0 channels; waves 4-7: batch1 channels; waves 8,9: aux for b0,b1.
__global__ __launch_bounds__(640, 2) void k_fused(
    const float* __restrict__ x,        // [B,129,250]
    const unsigned short* __restrict__ ahi,
    const unsigned short* __restrict__ alo,
    const float* __restrict__ w2t,      // [129,548] (row 128 used)
    const float* __restrict__ bias2,
    const float* __restrict__ conv_w,
    const float* __restrict__ conv_b,
    const float* __restrict__ dt_bias,
    const float* __restrict__ A_log,
    const float* __restrict__ Dv,
    const float* __restrict__ norm_w,
    const float* __restrict__ vv,
    const float* __restrict__ head_b,
    float* __restrict__ out)
{
    __shared__ short xh[16 * XK];             // bf16-hi of x chunk, [col][k]
    __shared__ short xl[16 * XK];             // bf16-lo
    __shared__ float x128buf[2][2][TC];       // c=128 raw, [parity][batch][tt]
    __shared__ float zxbuf[DPROJ * ZR];       // [j][col], col = b*8+tt
    __shared__ float bcbuf[2][TC][32];        // [batch][tt][0..15 B | 16..31 C]
    __shared__ float dtbuf[2][TC][NHEADS];
    __shared__ float dAbuf[2][TC][NHEADS];
    __shared__ float smp[2][2][TC][8];        // [parity][batch][tt][2w(+1)]

    const int b2   = blockIdx.x;
    const int tid  = threadIdx.x;
    const int lane = tid & 63;
    const int wv   = tid >> 6;                // 0..9
    const bool isMain = (wv < 8);
    const int mb   = isMain ? (wv >> 2) : (wv - 8);
    const int p    = ((wv & 3) << 6) | lane;  // main channel (valid if isMain)
    const int q    = lane;
    const int tcol = lane & 15;
    const int quad = lane >> 4;
    const bool isFold = isMain && ((wv & 3) == 0);   // waves 0 (b0) and 4 (b1)

    const float* w128 = w2t + (size_t)128 * DPROJ;

    float bz = 0.f, bx = 0.f, w1z = 0.f, w1x = 0.f;
    float cw0 = 0.f, cw1 = 0.f, cw2 = 0.f, cw3 = 0.f, ccb = 0.f;
    float dtb = 0.f, Ah = 0.f, Dh = 0.f, nv = 0.f;
    if (isMain) {
        bz = bias2[p];          w1z = w128[p];
        bx = bias2[DINNER + p]; w1x = w128[DINNER + p];
        cw0 = conv_w[p * 4 + 0]; cw1 = conv_w[p * 4 + 1];
        cw2 = conv_w[p * 4 + 2]; cw3 = conv_w[p * 4 + 3];
        ccb = conv_b[p];
        Dh = Dv[p >> 6];
        nv = norm_w[p] * vv[p];
    } else if (q < 36) {
        bx  = bias2[2 * DINNER + q];
        w1x = w128[2 * DINNER + q];
        if (q < 32) {
            int ch = DINNER + q;
            cw0 = conv_w[ch * 4 + 0]; cw1 = conv_w[ch * 4 + 1];
            cw2 = conv_w[ch * 4 + 2]; cw3 = conv_w[ch * 4 + 3];
            ccb = conv_b[ch];
        } else {
            int h = q - 32;
            dtb = dt_bias[h];
            Ah  = -expf(A_log[h]);
        }
    }

    float za[TC], xa[TC], hs[DSTATE];
    float c1 = 0.f, c2 = 0.f, c3 = 0.f, outacc = 0.f;
#pragma unroll
    for (int n = 0; n < DSTATE; ++n) hs[n] = 0.f;

    const float* xb_aux = x + ((size_t)2 * b2 + mb) * NCH * NT;  // aux's batch
    const int hh = wv & 3;                                       // head (main)
    float2 pr[9];

    auto load_chunk = [&](int t0, auto Lc) {
        constexpr int L  = decltype(Lc)::value;
        constexpr int HP = (L >= 2) ? L / 2 : 1;
        constexpr int PAIRS = NCH * HP;
#pragma unroll
        for (int k = 0; k * 64 < PAIRS; ++k) {
            int u = lane + 64 * k;
            if (u < PAIRS) {
                int c = u / HP, tp = u - c * HP;
                pr[k] = *(const float2*)(xb_aux + c * NT + t0 + 2 * tp);
            }
        }
    };
    auto store_chunk = [&](auto Lc, int nxtpar) {
        constexpr int L  = decltype(Lc)::value;
        constexpr int HP = (L >= 2) ? L / 2 : 1;
        constexpr int PAIRS = NCH * HP;
#pragma unroll
        for (int k = 0; k * 64 < PAIRS; ++k) {
            int u = lane + 64 * k;
            if (u < PAIRS) {
                int c = u / HP, tp = u - c * HP;
                float2 v = pr[k];
                if (c < 128) {
                    int row = mb * 8 + 2 * tp;
                    unsigned short h0 = f2bf(v.x), h1 = f2bf(v.y);
                    xh[row * XK + c]       = (short)h0;
                    xh[(row + 1) * XK + c] = (short)h1;
                    xl[row * XK + c]       = (short)f2bf(v.x - bf2f(h0));
                    xl[(row + 1) * XK + c] = (short)f2bf(v.y - bf2f(h1));
                } else {
                    x128buf[nxtpar][mb][2 * tp]     = v.x;
                    x128buf[nxtpar][mb][2 * tp + 1] = v.y;
                }
            }
        }
    };

    // prologue: stage chunk 0 (parity 0)
    if (!isMain) { load_chunk(0, IC<TC>{}); store_chunk(IC<TC>{}, 0); }
    __syncthreads();

    auto stage = [&](auto CLc, auto NLc, int s) {
        constexpr int CL = decltype(CLc)::value;
        constexpr int NL = decltype(NLc)::value;
        const int cur = s & 1;

        // ---------------- P1: MFMA GEMM ----------------
        if (isMain) {
            short8 bh[KS4], bl[KS4];
#pragma unroll
            for (int ks = 0; ks < KS4; ++ks) {
                bh[ks] = *(const short8*)&xh[tcol * XK + ks * 32 + quad * 8];
                bl[ks] = *(const short8*)&xl[tcol * XK + ks * 32 + quad * 8];
            }
            for (int mt = wv; mt < MT; mt += 8) {
                f32x4 a0 = {0.f, 0.f, 0.f, 0.f};
                f32x4 a1 = {0.f, 0.f, 0.f, 0.f};
#pragma unroll
                for (int ks = 0; ks < KS4; ++ks) {
                    size_t fo = (((size_t)(mt * KS4 + ks)) * 64 + lane) * 8;
                    short8 ah = *(const short8*)(ahi + fo);
                    short8 al = *(const short8*)(alo + fo);
                    a0 = __builtin_amdgcn_mfma_f32_16x16x32_bf16(ah, bh[ks], a0, 0, 0, 0);
                    a1 = __builtin_amdgcn_mfma_f32_16x16x32_bf16(ah, bl[ks], a1, 0, 0, 0);
                    a1 = __builtin_amdgcn_mfma_f32_16x16x32_bf16(al, bh[ks], a1, 0, 0, 0);
                }
#pragma unroll
                for (int r = 0; r < 4; ++r) {
                    int j = mt * 16 + quad * 4 + r;
                    if (j < DPROJ) zxbuf[j * ZR + tcol] = a0[r] + a1[r];
                }
            }
        } else {
            if constexpr (NL > 0) load_chunk((s + 1) * TC, IC<NL>{});
        }
        __syncthreads();   // A: zxbuf ready; xh/xl consumed

        // ---------------- P2a ----------------
        if (isMain) {
            if (isFold && s > 0 && lane < TC) {   // fold prev chunk's partials
                const float* sp = smp[(s - 1) & 1][mb][lane];
                float s1 = sp[0] + sp[2] + sp[4] + sp[6];
                float s2 = sp[1] + sp[3] + sp[5] + sp[7];
                outacc = fmaf(s2, rsqrtf(fmaf(s1, 1.f / DINNER, 1e-5f)), outacc);
            }
#pragma unroll
            for (int tt = 0; tt < CL; ++tt) {
                float xm = x128buf[cur][mb][tt];
                int col = mb * 8 + tt;
                float zraw = zxbuf[p * ZR + col] + bz + w1z * xm;
                float xraw = zxbuf[(DINNER + p) * ZR + col] + bx + w1x * xm;
                float cv = fmaf(cw3, xraw, fmaf(cw2, c1, fmaf(cw1, c2, fmaf(cw0, c3, ccb))));
                c3 = c2; c2 = c1; c1 = xraw;
                xa[tt] = silu_f(cv);
                za[tt] = silu_f(zraw);
            }
        } else {
            if constexpr (NL > 0) store_chunk(IC<NL>{}, (s + 1) & 1);
            if (q < 32) {
#pragma unroll
                for (int tt = 0; tt < CL; ++tt) {
                    float xm = x128buf[cur][mb][tt];
                    float raw = zxbuf[(2 * DINNER + q) * ZR + mb * 8 + tt] + bx + w1x * xm;
                    float cv = fmaf(cw3, raw, fmaf(cw2, c1, fmaf(cw1, c2, fmaf(cw0, c3, ccb))));
                    c3 = c2; c2 = c1; c1 = raw;
                    bcbuf[mb][tt][q] = silu_f(cv);
                }
            } else if (q < 36) {
                int h = q - 32;
#pragma unroll
                for (int tt = 0; tt < CL; ++tt) {
                    float xm = x128buf[cur][mb][tt];
                    float val = zxbuf[(544 + h) * ZR + mb * 8 + tt] + bx + w1x * xm + dtb;
                    float dt = (val > 20.f) ? val : log1pf(expf(val));
                    dtbuf[mb][tt][h] = dt;
                    dAbuf[mb][tt][h] = __expf(dt * Ah);
                }
            }
        }
        __syncthreads();   // B: bc/dt ready; xh/xl restaged

        // ---------------- P2b: scan + DPP reductions ----------------
        if (isMain) {
#pragma unroll
            for (int tt = 0; tt < CL; ++tt) {
                float xv  = xa[tt];
                float g   = za[tt];
                float dtv = dtbuf[mb][tt][hh];
                float dAv = dAbuf[mb][tt][hh];
                float bcv = bcbuf[mb][tt][lane & 31];
                float dx = dtv * xv;
                float y0 = 0.f, y1 = 0.f, y2 = 0.f, y3 = 0.f;
#pragma unroll
                for (int n = 0; n < 4; ++n) {
                    float b0 = rdlane(bcv, n),      cc0 = rdlane(bcv, DSTATE + n);
                    float b1 = rdlane(bcv, 4 + n),  cc1 = rdlane(bcv, DSTATE + 4 + n);
                    float b2v = rdlane(bcv, 8 + n), cc2 = rdlane(bcv, DSTATE + 8 + n);
                    float b3 = rdlane(bcv, 12 + n), cc3 = rdlane(bcv, DSTATE + 12 + n);
                    hs[n]      = fmaf(hs[n],      dAv, dx * b0);  y0 = fmaf(hs[n],      cc0, y0);
                    hs[4 + n]  = fmaf(hs[4 + n],  dAv, dx * b1);  y1 = fmaf(hs[4 + n],  cc1, y1);
                    hs[8 + n]  = fmaf(hs[8 + n],  dAv, dx * b2v); y2 = fmaf(hs[8 + n],  cc2, y2);
                    hs[12 + n] = fmaf(hs[12 + n], dAv, dx * b3);  y3 = fmaf(hs[12 + n], cc3, y3);
                }
                float val = fmaf(Dh, xv, (y0 + y1) + (y2 + y3)) * g;
                float s1 = wave_sum63(val * val);
                float s2 = wave_sum63(val * nv);
                if (lane == 63) {
                    smp[cur][mb][tt][2 * (wv & 3)]     = s1;
                    smp[cur][mb][tt][2 * (wv & 3) + 1] = s2;
                }
            }
        }
        // no barrier here: next P1 doesn't touch smp/bcbuf; zxbuf reads done pre-B
    };

    stage(IC<8>{}, IC<8>{}, 0);
    for (int s = 1; s <= 29; ++s) stage(IC<8>{}, IC<8>{}, s);
    stage(IC<8>{}, IC<2>{}, 30);
    stage(IC<2>{}, IC<0>{}, 31);
    __syncthreads();

    if (isFold) {
        if (lane < 2) {   // fold tail chunk (stage 31, parity 1, CL=2)
            const float* sp = smp[1][mb][lane];
            float s1 = sp[0] + sp[2] + sp[4] + sp[6];
            float s2 = sp[1] + sp[3] + sp[5] + sp[7];
            outacc = fmaf(s2, rsqrtf(fmaf(s1, 1.f / DINNER, 1e-5f)), outacc);
        }
        float tot = wave_sum63(outacc);
        if (lane == 63) out[2 * b2 + mb] = head_b[0] + tot * (1.f / NT);
    }
}

extern "C" void kernel_launch(void* const* d_in, const int* in_sizes, int n_in,
                              void* d_out, int out_size, void* d_ws, size_t ws_size,
                              hipStream_t stream) {
    const float* x         = (const float*)d_in[0];
    const float* mixer_w   = (const float*)d_in[1];
    const float* mixer_b   = (const float*)d_in[2];
    const float* in_proj_w = (const float*)d_in[3];
    const float* conv_w    = (const float*)d_in[4];
    const float* conv_b    = (const float*)d_in[5];
    const float* dt_bias   = (const float*)d_in[6];
    const float* A_log     = (const float*)d_in[7];
    const float* Dp        = (const float*)d_in[8];
    const float* norm_w    = (const float*)d_in[9];
    const float* out_proj_w= (const float*)d_in[10];
    const float* head_w    = (const float*)d_in[11];
    const float* head_b    = (const float*)d_in[12];
    float* out = (float*)d_out;

    int B = in_sizes[0] / (NCH * NT);   // 512

    float* ws    = (float*)d_ws;
    float* w2t   = ws;                          // 129*548 f32
    float* bias2 = w2t + (size_t)NCH * DPROJ;
    float* vvp   = bias2 + DPROJ;
    unsigned short* ahi = (unsigned short*)(vvp + DINNER);       // 35*4*64*8 shorts
    unsigned short* alo = ahi + (size_t)MT * KS4 * 64 * 8;

    k_prep_w2<<<DPROJ, 256, 0, stream>>>(in_proj_w, mixer_w, mixer_b, w2t, bias2);
    k_prep_v<<<1, 256, 0, stream>>>(head_w, out_proj_w, vvp);
    k_prep_frag<<<dim3(MT, KS4), 64, 0, stream>>>(w2t, ahi, alo);
    k_fused<<<B / 2, 640, 0, stream>>>(x, ahi, alo, w2t, bias2, conv_w, conv_b,
                                       dt_bias, A_log, Dp, norm_w, vvp, head_b, out);
}